// Round 3
// baseline (570.699 us; speedup 1.0000x reference)
//
#include <hip/hip_runtime.h>

// Problem constants
#define N_    4
#define C_    256
#define PS_   4096      // 64*64 source pixels
#define PO_   16384     // 128*128 output pixels
#define COMP_ 64
#define QCH_  100       // K*K*R*R
#define KK_   25

// ---------------------------------------------------------------------------
// Kernel 0: W_eff[o,c] = sum_m w_bott[o,m]*w_conv2[m,c] + w_bott[o,256+c]
//           b_eff[o]   = sum_m w_bott[o,m]*b_conv2[m]
__global__ __launch_bounds__(256) void k_weff(const float* __restrict__ w_bott,
        const float* __restrict__ w_conv2, const float* __restrict__ b_conv2,
        float* __restrict__ Weff, float* __restrict__ beff) {
    int o = blockIdx.x, c = threadIdx.x;
    __shared__ float wb[512];
    wb[c]       = w_bott[o * 512 + c];
    wb[c + 256] = w_bott[o * 512 + 256 + c];
    __syncthreads();
    float acc = wb[256 + c];
    #pragma unroll 8
    for (int m = 0; m < 256; ++m)
        acc += wb[m] * w_conv2[m * 256 + c];
    Weff[o * 256 + c] = acc;
    if (c == 0) {
        float be = 0.f;
        for (int m = 0; m < 256; ++m) be += wb[m] * b_conv2[m];
        beff[o] = be;
    }
}

// ---------------------------------------------------------------------------
// Kernel 1: channel compressor 1x1 — weights via uniform (scalar) loads, no LDS
__global__ __launch_bounds__(256) void k_compress(const float* __restrict__ x,
        const float* __restrict__ w_cc, const float* __restrict__ b_cc,
        float* __restrict__ comp) {
    int n = blockIdx.z, m0 = blockIdx.y * 16, px = blockIdx.x * 256 + threadIdx.x;
    float acc[16];
    #pragma unroll
    for (int m = 0; m < 16; ++m) acc[m] = b_cc[m0 + m];
    const float* xb = x + n * C_ * PS_ + px;
    const float* wb = w_cc + m0 * 256;          // uniform base
    #pragma unroll 1
    for (int c0 = 0; c0 < 256; c0 += 8) {
        float xv[8];
        #pragma unroll
        for (int cc = 0; cc < 8; ++cc) xv[cc] = xb[(c0 + cc) * PS_];
        #pragma unroll
        for (int m = 0; m < 16; ++m) {
            #pragma unroll
            for (int cc = 0; cc < 8; ++cc)
                acc[m] += wb[m * 256 + c0 + cc] * xv[cc];
        }
    }
    float* cp = comp + (n * COMP_ + m0) * PS_ + px;
    #pragma unroll
    for (int m = 0; m < 16; ++m) cp[m * PS_] = acc[m];
}

// ---------------------------------------------------------------------------
// Kernel 2: content encoder 3x3 (pad 1). Neighborhood from LDS (staged once,
// all 64 channels); weights via wave-uniform scalar loads from global.
// grid 256 = (n, 8x8 tiles of 8x8 px); threads 256 = 4 q-groups x 64 px
__global__ __launch_bounds__(256) void k_encode(const float* __restrict__ comp,
        const float* __restrict__ w_ce, const float* __restrict__ b_ce,
        float* __restrict__ mask_raw) {
    int b = blockIdx.x;
    int n = b >> 6, tile = b & 63;
    int ty0 = (tile >> 3) << 3, tx0 = (tile & 7) << 3;
    int tid = threadIdx.x;
    int px = tid & 63;
    int sy = px >> 3, sx = px & 7;
    int q0 = __builtin_amdgcn_readfirstlane(tid >> 6) * 25;   // wave-uniform q-group
    __shared__ float ct[64 * 100];   // 64 ch x 10x10 tile (25.6 KB)
    for (int idx = tid; idx < 6400; idx += 256) {
        int cc = idx / 100, r = idx - cc * 100;
        int yy = ty0 - 1 + r / 10, xx = tx0 - 1 + (r % 10);
        float v = 0.f;
        if ((unsigned)yy < 64u && (unsigned)xx < 64u)
            v = comp[(n * COMP_ + cc) * PS_ + yy * 64 + xx];
        ct[cc * 100 + r] = v;
    }
    __syncthreads();
    float acc[25];
    #pragma unroll
    for (int q = 0; q < 25; ++q) acc[q] = b_ce[q0 + q];
    #pragma unroll 1
    for (int cg = 0; cg < 8; ++cg) {
        // load 8 channels x 9 taps of the neighborhood into VGPRs
        float nb[72];
        const float* cb = ct + (cg * 8) * 100 + sy * 10 + sx;
        #pragma unroll
        for (int c = 0; c < 8; ++c) {
            #pragma unroll
            for (int dy = 0; dy < 3; ++dy) {
                #pragma unroll
                for (int dx = 0; dx < 3; ++dx)
                    nb[c * 9 + dy * 3 + dx] = cb[c * 100 + dy * 10 + dx];
            }
        }
        // weights: w_ce[(q)*576 + cg*72 + u], u = c*9+t  — fully wave-uniform
        const float* wb = w_ce + q0 * 576 + cg * 72;
        #pragma unroll
        for (int q = 0; q < 25; ++q) {
            const float* wq = wb + q * 576;
            #pragma unroll
            for (int u = 0; u < 72; ++u)
                acc[q] += wq[u] * nb[u];
        }
    }
    float* mp = mask_raw + (n * QCH_ + q0) * PS_ + (ty0 + sy) * 64 + (tx0 + sx);
    #pragma unroll
    for (int q = 0; q < 25; ++q) mp[q * PS_] = acc[q];
}

// ---------------------------------------------------------------------------
// Kernel 3: Y[n,o,p] = sum_c Weff[o,c]*high[n,c,p]  — 128x128 tile, 8x8/thread
__global__ __launch_bounds__(256) void k_ygemm(const float* __restrict__ Weff,
        const float* __restrict__ high, float* __restrict__ Y) {
    int n = blockIdx.z, o0 = blockIdx.y * 128, p0 = blockIdx.x * 128;
    int tid = threadIdx.x;
    int ty = tid >> 4, tx = tid & 15;
    __shared__ float As[16 * 132];   // [k][o], padded to 132
    __shared__ float Bs[16 * 128];   // [k][p]
    float acc[8][8] = {};
    #pragma unroll 1
    for (int k0 = 0; k0 < 256; k0 += 16) {
        __syncthreads();
        #pragma unroll
        for (int j = 0; j < 2; ++j) {
            int lin = tid + j * 256;
            int oo = lin >> 2, kq = (lin & 3) * 4;
            float4 a4 = *reinterpret_cast<const float4*>(Weff + (o0 + oo) * 256 + k0 + kq);
            As[(kq + 0) * 132 + oo] = a4.x;
            As[(kq + 1) * 132 + oo] = a4.y;
            As[(kq + 2) * 132 + oo] = a4.z;
            As[(kq + 3) * 132 + oo] = a4.w;
            int row = lin >> 5, f4 = lin & 31;
            float4 b4 = *reinterpret_cast<const float4*>(high + (n * C_ + k0 + row) * PS_ + p0 + f4 * 4);
            *reinterpret_cast<float4*>(Bs + row * 128 + f4 * 4) = b4;
        }
        __syncthreads();
        #pragma unroll
        for (int kk = 0; kk < 16; ++kk) {
            float4 a0 = *reinterpret_cast<const float4*>(As + kk * 132 + ty * 8);
            float4 a1 = *reinterpret_cast<const float4*>(As + kk * 132 + ty * 8 + 4);
            float4 b0 = *reinterpret_cast<const float4*>(Bs + kk * 128 + tx * 8);
            float4 b1 = *reinterpret_cast<const float4*>(Bs + kk * 128 + tx * 8 + 4);
            float av[8] = {a0.x, a0.y, a0.z, a0.w, a1.x, a1.y, a1.z, a1.w};
            float bv[8] = {b0.x, b0.y, b0.z, b0.w, b1.x, b1.y, b1.z, b1.w};
            #pragma unroll
            for (int i = 0; i < 8; ++i) {
                #pragma unroll
                for (int jj = 0; jj < 8; ++jj)
                    acc[i][jj] += av[i] * bv[jj];
            }
        }
    }
    #pragma unroll
    for (int i = 0; i < 8; ++i) {
        float* yp = Y + (n * C_ + o0 + ty * 8 + i) * PS_ + p0 + tx * 8;
        float4 r0 = {acc[i][0], acc[i][1], acc[i][2], acc[i][3]};
        float4 r1 = {acc[i][4], acc[i][5], acc[i][6], acc[i][7]};
        *reinterpret_cast<float4*>(yp) = r0;
        *reinterpret_cast<float4*>(yp + 4) = r1;
    }
}

// ---------------------------------------------------------------------------
// Kernel 4: softmax(25) + CARAFE reassembly. xt is channel-innermost so the
// inner loop reads 4 channels per ds_read_b128.
// grid 256 = (n, 8x8 source tile); threads 256 = 16x16 output pixels
__global__ __launch_bounds__(256) void k_carafe(const float* __restrict__ Y,
        const float* __restrict__ mask_raw, const float* __restrict__ beff,
        float* __restrict__ xout) {
    int b = blockIdx.x;
    int n = b >> 6, tile = b & 63;
    int sh0 = (tile >> 3) << 3, sw0 = (tile & 7) << 3;
    int tid = threadIdx.x;
    int ty = tid >> 4, tx = tid & 15;
    int oi = sh0 * 2 + ty, oj = sw0 * 2 + tx;
    int h = sh0 + (ty >> 1), w = sw0 + (tx >> 1);
    int sub = ((ty & 1) << 1) | (tx & 1);
    float v[25];
    const float* mp = mask_raw + n * QCH_ * PS_ + h * 64 + w;
    #pragma unroll
    for (int k = 0; k < 25; ++k) v[k] = mp[(k * 4 + sub) * PS_];
    float mx = v[0];
    #pragma unroll
    for (int k = 1; k < 25; ++k) mx = fmaxf(mx, v[k]);
    float s = 0.f;
    #pragma unroll
    for (int k = 0; k < 25; ++k) { v[k] = __expf(v[k] - mx); s += v[k]; }
    float inv = 1.f / s;
    #pragma unroll
    for (int k = 0; k < 25; ++k) v[k] *= inv;

    __shared__ float xt[4608];       // [12x12 px][32 ch]  (18.4 KB)
    int sbase = ((ty >> 1) * 12 + (tx >> 1)) * 32;
    float* hp = xout + n * C_ * PO_ + oi * 128 + oj;
    for (int cg = 0; cg < 8; ++cg) {
        __syncthreads();
        for (int idx = tid; idx < 4608; idx += 256) {
            int sp = idx >> 5, cc = idx & 31;
            int row = sp / 12, col = sp - row * 12;
            int yy = sh0 - 2 + row, xx = sw0 - 2 + col;
            float val = 0.f;
            if ((unsigned)yy < 64u && (unsigned)xx < 64u)
                val = Y[(n * C_ + cg * 32 + cc) * PS_ + yy * 64 + xx];
            xt[sp * 32 + cc] = val;
        }
        __syncthreads();
        #pragma unroll 1
        for (int c4 = 0; c4 < 8; ++c4) {
            int ch = cg * 32 + c4 * 4;
            float ax = beff[ch], ay = beff[ch + 1], az = beff[ch + 2], aw = beff[ch + 3];
            const float* base = xt + sbase + c4 * 4;
            #pragma unroll
            for (int ky = 0; ky < 5; ++ky) {
                #pragma unroll
                for (int kx = 0; kx < 5; ++kx) {
                    float4 yv = *reinterpret_cast<const float4*>(base + (ky * 12 + kx) * 32);
                    float m = v[ky * 5 + kx];
                    ax += m * yv.x; ay += m * yv.y; az += m * yv.z; aw += m * yv.w;
                }
            }
            hp[(ch + 0) * PO_] = ax;
            hp[(ch + 1) * PO_] = ay;
            hp[(ch + 2) * PO_] = az;
            hp[(ch + 3) * PO_] = aw;
        }
    }
}

// ---------------------------------------------------------------------------
// Kernel 5: per-channel BN stats -> scale/shift. One block per channel.
__global__ __launch_bounds__(256) void k_stats(const float* __restrict__ xb,
        const float* __restrict__ gamma, const float* __restrict__ beta,
        float* __restrict__ scale, float* __restrict__ shift) {
    int o = blockIdx.x, tid = threadIdx.x;
    float s = 0.f, s2 = 0.f;
    for (int n = 0; n < 4; ++n) {
        const float* p = xb + (n * C_ + o) * PO_;
        #pragma unroll 4
        for (int i = 0; i < 64; ++i) {
            float v = p[i * 256 + tid];
            s += v; s2 += v * v;
        }
    }
    __shared__ float rs[256], rq[256];
    rs[tid] = s; rq[tid] = s2;
    __syncthreads();
    for (int off = 128; off > 0; off >>= 1) {
        if (tid < off) { rs[tid] += rs[tid + off]; rq[tid] += rq[tid + off]; }
        __syncthreads();
    }
    if (tid == 0) {
        float mean = rs[0] * (1.f / 65536.f);
        float var  = rq[0] * (1.f / 65536.f) - mean * mean;
        float sc = rsqrtf(var + 1e-5f) * gamma[o];
        scale[o] = sc;
        shift[o] = beta[o] - mean * sc;
    }
}

// ---------------------------------------------------------------------------
// Kernel 6: in-place normalize + ReLU on d_out (f32), 4 elems/thread
__global__ __launch_bounds__(256) void k_norm(float* __restrict__ xb,
        const float* __restrict__ scale, const float* __restrict__ shift) {
    int base = (blockIdx.x * 256 + threadIdx.x) * 4;
    int o = (base >> 14) & 255;
    float sc = scale[o], sh = shift[o];
    float4 v = *reinterpret_cast<const float4*>(xb + base);
    v.x = fmaxf(v.x * sc + sh, 0.f);
    v.y = fmaxf(v.y * sc + sh, 0.f);
    v.z = fmaxf(v.z * sc + sh, 0.f);
    v.w = fmaxf(v.w * sc + sh, 0.f);
    *reinterpret_cast<float4*>(xb + base) = v;
}

// ---------------------------------------------------------------------------
extern "C" void kernel_launch(void* const* d_in, const int* in_sizes, int n_in,
                              void* d_out, int out_size, void* d_ws, size_t ws_size,
                              hipStream_t stream) {
    // input order (all float32): low_feature(unused), high_feature, w_cc, b_cc,
    //   w_ce, b_ce, w_conv2, b_conv2, w_bott, gamma, beta
    const float* high    = (const float*)d_in[1];
    const float* w_cc    = (const float*)d_in[2];
    const float* b_cc    = (const float*)d_in[3];
    const float* w_ce    = (const float*)d_in[4];
    const float* b_ce    = (const float*)d_in[5];
    const float* w_conv2 = (const float*)d_in[6];
    const float* b_conv2 = (const float*)d_in[7];
    const float* w_bott  = (const float*)d_in[8];
    const float* gamma   = (const float*)d_in[9];
    const float* beta    = (const float*)d_in[10];

    char* ws = (char*)d_ws;
    float* Weff  = (float*)(ws + 0);          // 65536 f32
    float* beff  = (float*)(ws + 262144);     // 256 f32
    float* scale = (float*)(ws + 263168);     // 256 f32
    float* shift = (float*)(ws + 264192);     // 256 f32
    float* comp  = (float*)(ws + 265216);     // 4*64*4096 f32 = 4 MiB
    float* mask  = (float*)(ws + 4459520);    // 4*100*4096 f32 = 6.25 MiB
    float* Y     = (float*)(ws + 11013120);   // 4*256*4096 f32 = 16 MiB
    float* xout  = (float*)d_out;             // pre-BN x in d_out, normalized in place

    k_weff    <<<256, 256, 0, stream>>>(w_bott, w_conv2, b_conv2, Weff, beff);
    k_compress<<<dim3(16, 4, 4), 256, 0, stream>>>(high, w_cc, b_cc, comp);
    k_encode  <<<256, 256, 0, stream>>>(comp, w_ce, b_ce, mask);
    k_ygemm   <<<dim3(32, 2, 4), 256, 0, stream>>>(Weff, high, Y);
    k_carafe  <<<256, 256, 0, stream>>>(Y, mask, beff, xout);
    k_stats   <<<256, 256, 0, stream>>>(xout, gamma, beta, scale, shift);
    k_norm    <<<16384, 256, 0, stream>>>(xout, scale, shift);
}

// Round 4
// 389.963 us; speedup vs baseline: 1.4635x; 1.4635x over previous
//
#include <hip/hip_runtime.h>
#include <hip/hip_bf16.h>

// Problem constants
#define N_    4
#define C_    256
#define PS_   4096      // 64*64 source pixels
#define PO_   16384     // 128*128 output pixels
#define COMP_ 64
#define QCH_  100       // K*K*R*R
#define KK_   25

typedef unsigned short u16;
typedef __attribute__((ext_vector_type(8))) short short8;   // 8 bf16 = 4 VGPR
typedef __attribute__((ext_vector_type(4))) float f32x4;

__device__ __forceinline__ u16 f2bu(float f) {
    __hip_bfloat16 h = __float2bfloat16(f);
    return __builtin_bit_cast(u16, h);
}

// ---------------------------------------------------------------------------
// Kernel 0: W_eff[o,c] = sum_m w_bott[o,m]*w_conv2[m,c] + w_bott[o,256+c]
//           b_eff[o]   = sum_m w_bott[o,m]*b_conv2[m]
__global__ __launch_bounds__(256) void k_weff(const float* __restrict__ w_bott,
        const float* __restrict__ w_conv2, const float* __restrict__ b_conv2,
        float* __restrict__ Weff, float* __restrict__ beff) {
    int o = blockIdx.x, c = threadIdx.x;
    __shared__ float wb[512];
    wb[c]       = w_bott[o * 512 + c];
    wb[c + 256] = w_bott[o * 512 + 256 + c];
    __syncthreads();
    float acc = wb[256 + c];
    #pragma unroll 8
    for (int m = 0; m < 256; ++m)
        acc += wb[m] * w_conv2[m * 256 + c];
    Weff[o * 256 + c] = acc;
    if (c == 0) {
        float be = 0.f;
        for (int m = 0; m < 256; ++m) be += wb[m] * b_conv2[m];
        beff[o] = be;
    }
}

// ---------------------------------------------------------------------------
// Kernel 1: channel compressor 1x1 (round-2 LDS-broadcast form)
__global__ __launch_bounds__(256) void k_compress(const float* __restrict__ x,
        const float* __restrict__ w_cc, const float* __restrict__ b_cc,
        float* __restrict__ comp) {
    int n = blockIdx.z, m0 = blockIdx.y * 16, px = blockIdx.x * 256 + threadIdx.x;
    __shared__ float wl[16 * 256];
    for (int i = threadIdx.x; i < 16 * 256; i += 256)
        wl[i] = w_cc[(m0 + (i >> 8)) * 256 + (i & 255)];
    __syncthreads();
    float acc[16];
    #pragma unroll
    for (int m = 0; m < 16; ++m) acc[m] = b_cc[m0 + m];
    const float* xb = x + n * C_ * PS_ + px;
    #pragma unroll 1
    for (int c0 = 0; c0 < 256; c0 += 8) {
        float xv[8];
        #pragma unroll
        for (int cc = 0; cc < 8; ++cc) xv[cc] = xb[(c0 + cc) * PS_];
        #pragma unroll
        for (int m = 0; m < 16; ++m) {
            #pragma unroll
            for (int cc = 0; cc < 8; ++cc)
                acc[m] += wl[m * 256 + c0 + cc] * xv[cc];
        }
    }
    float* cp = comp + (n * COMP_ + m0) * PS_ + px;
    #pragma unroll
    for (int m = 0; m < 16; ++m) cp[m * PS_] = acc[m];
}

// ---------------------------------------------------------------------------
// Kernel 2a: Wb[q][u] bf16, q padded 100->128  (u = c*9 + dy*3 + dx, 576)
__global__ __launch_bounds__(256) void k_prepw(const float* __restrict__ w_ce,
        u16* __restrict__ Wb) {
    int i = blockIdx.x * 256 + threadIdx.x;     // over 128*576
    int q = i / 576, u = i - q * 576;
    float v = (q < 100) ? w_ce[q * 576 + u] : 0.f;
    Wb[i] = f2bu(v);
}

// ---------------------------------------------------------------------------
// Kernel 2b: im2col of comp -> Icol[gpx][u] bf16 (u contiguous), zero-padded 3x3
// grid 256 = (n, 8x8 tiles of 8x8 px)
__global__ __launch_bounds__(256) void k_im2col(const float* __restrict__ comp,
        u16* __restrict__ Icol) {
    int b = blockIdx.x;
    int n = b >> 6, tile = b & 63;
    int ty0 = (tile >> 3) << 3, tx0 = (tile & 7) << 3;
    int tid = threadIdx.x;
    __shared__ float ct[64 * 100];   // 64 ch x 10x10 halo tile
    for (int idx = tid; idx < 6400; idx += 256) {
        int cc = idx / 100, r = idx - cc * 100;
        int yy = ty0 - 1 + r / 10, xx = tx0 - 1 + (r % 10);
        float v = 0.f;
        if ((unsigned)yy < 64u && (unsigned)xx < 64u)
            v = comp[(n * COMP_ + cc) * PS_ + yy * 64 + xx];
        ct[idx] = v;
    }
    __syncthreads();
    // thread-invariant u decode, hoisted
    int u0 = tid * 2, u1 = u0 + 1;
    int c0 = (unsigned)u0 / 9u, t0 = u0 - c0 * 9;
    int c1 = (unsigned)u1 / 9u, t1 = u1 - c1 * 9;
    int off0 = c0 * 100 + (t0 / 3) * 10 + (t0 % 3);
    int off1 = c1 * 100 + (t1 / 3) * 10 + (t1 % 3);
    int u2 = 512 + tid * 2, u3 = u2 + 1;   // only tid<32
    int c2 = (unsigned)u2 / 9u, t2 = u2 - c2 * 9;
    int c3 = (unsigned)u3 / 9u, t3 = u3 - c3 * 9;
    int off2 = c2 * 100 + (t2 / 3) * 10 + (t2 % 3);
    int off3 = c3 * 100 + (t3 / 3) * 10 + (t3 % 3);
    #pragma unroll 1
    for (int px = 0; px < 64; ++px) {
        int py = px >> 3, pxx = px & 7;
        int base = py * 10 + pxx;
        int gpx = n * PS_ + (ty0 + py) * 64 + tx0 + pxx;
        u16* dst = Icol + gpx * 576;
        unsigned lo = f2bu(ct[off0 + base]);
        unsigned hi = f2bu(ct[off1 + base]);
        *reinterpret_cast<unsigned*>(dst + u0) = lo | (hi << 16);
        if (tid < 32) {
            unsigned lo2 = f2bu(ct[off2 + base]);
            unsigned hi2 = f2bu(ct[off3 + base]);
            *reinterpret_cast<unsigned*>(dst + u2) = lo2 | (hi2 << 16);
        }
    }
}

// ---------------------------------------------------------------------------
// Kernel 2c: encoder GEMM via MFMA: mask[q,gpx] = b_ce[q] + sum_u Wb[q,u]*Icol[gpx,u]
// M=128(pad 100), K=576, N=16384. Block: N-tile 128, full M. 4 waves x 2 m-tiles.
__global__ __launch_bounds__(256) void k_encode_mfma(const u16* __restrict__ Wb,
        const u16* __restrict__ Icol, const float* __restrict__ b_ce,
        float* __restrict__ mask_raw) {
    int tid = threadIdx.x;
    int wid = tid >> 6, lane = tid & 63;
    int col = lane & 15, quad = lane >> 4;
    int px0 = blockIdx.x * 128;
    __shared__ u16 As[128 * 40];   // [m][k-chunk], stride 40 (16B-aligned frags)
    __shared__ u16 Bs[128 * 40];   // [n][k-chunk]
    f32x4 acc[2][8] = {};
    #pragma unroll 1
    for (int k0 = 0; k0 < 576; k0 += 32) {
        __syncthreads();
        #pragma unroll
        for (int it = 0; it < 2; ++it) {
            int s = tid + it * 256;
            int row = s >> 2, seg = s & 3;
            short8 av = *reinterpret_cast<const short8*>(Wb + row * 576 + k0 + seg * 8);
            *reinterpret_cast<short8*>(&As[row * 40 + seg * 8]) = av;
            short8 bv = *reinterpret_cast<const short8*>(Icol + (px0 + row) * 576 + k0 + seg * 8);
            *reinterpret_cast<short8*>(&Bs[row * 40 + seg * 8]) = bv;
        }
        __syncthreads();
        short8 a0 = *reinterpret_cast<const short8*>(&As[(wid * 32 + col) * 40 + quad * 8]);
        short8 a1 = *reinterpret_cast<const short8*>(&As[(wid * 32 + 16 + col) * 40 + quad * 8]);
        #pragma unroll
        for (int nt = 0; nt < 8; ++nt) {
            short8 b = *reinterpret_cast<const short8*>(&Bs[(nt * 16 + col) * 40 + quad * 8]);
            acc[0][nt] = __builtin_amdgcn_mfma_f32_16x16x32_bf16(a0, b, acc[0][nt], 0, 0, 0);
            acc[1][nt] = __builtin_amdgcn_mfma_f32_16x16x32_bf16(a1, b, acc[1][nt], 0, 0, 0);
        }
    }
    int nimg = px0 >> 12;
    int pbase = px0 & 4095;
    #pragma unroll
    for (int mi = 0; mi < 2; ++mi) {
        int qbase = (wid * 2 + mi) * 16 + quad * 4;
        #pragma unroll
        for (int r = 0; r < 4; ++r) {
            int q = qbase + r;
            if (q < 100) {
                float bias = b_ce[q];
                float* mp = mask_raw + (nimg * QCH_ + q) * PS_ + pbase + col;
                #pragma unroll
                for (int nt = 0; nt < 8; ++nt)
                    mp[nt * 16] = acc[mi][nt][r] + bias;
            }
        }
    }
}

// ---------------------------------------------------------------------------
// Kernel 3: Y[n,o,p] = sum_c Weff[o,c]*high[n,c,p]  — 128x128 tile, 8x8/thread
__global__ __launch_bounds__(256) void k_ygemm(const float* __restrict__ Weff,
        const float* __restrict__ high, float* __restrict__ Y) {
    int n = blockIdx.z, o0 = blockIdx.y * 128, p0 = blockIdx.x * 128;
    int tid = threadIdx.x;
    int ty = tid >> 4, tx = tid & 15;
    __shared__ float As[16 * 132];
    __shared__ float Bs[16 * 128];
    float acc[8][8] = {};
    #pragma unroll 1
    for (int k0 = 0; k0 < 256; k0 += 16) {
        __syncthreads();
        #pragma unroll
        for (int j = 0; j < 2; ++j) {
            int lin = tid + j * 256;
            int oo = lin >> 2, kq = (lin & 3) * 4;
            float4 a4 = *reinterpret_cast<const float4*>(Weff + (o0 + oo) * 256 + k0 + kq);
            As[(kq + 0) * 132 + oo] = a4.x;
            As[(kq + 1) * 132 + oo] = a4.y;
            As[(kq + 2) * 132 + oo] = a4.z;
            As[(kq + 3) * 132 + oo] = a4.w;
            int row = lin >> 5, f4 = lin & 31;
            float4 b4 = *reinterpret_cast<const float4*>(high + (n * C_ + k0 + row) * PS_ + p0 + f4 * 4);
            *reinterpret_cast<float4*>(Bs + row * 128 + f4 * 4) = b4;
        }
        __syncthreads();
        #pragma unroll
        for (int kk = 0; kk < 16; ++kk) {
            float4 a0 = *reinterpret_cast<const float4*>(As + kk * 132 + ty * 8);
            float4 a1 = *reinterpret_cast<const float4*>(As + kk * 132 + ty * 8 + 4);
            float4 b0 = *reinterpret_cast<const float4*>(Bs + kk * 128 + tx * 8);
            float4 b1 = *reinterpret_cast<const float4*>(Bs + kk * 128 + tx * 8 + 4);
            float av[8] = {a0.x, a0.y, a0.z, a0.w, a1.x, a1.y, a1.z, a1.w};
            float bv[8] = {b0.x, b0.y, b0.z, b0.w, b1.x, b1.y, b1.z, b1.w};
            #pragma unroll
            for (int i = 0; i < 8; ++i) {
                #pragma unroll
                for (int jj = 0; jj < 8; ++jj)
                    acc[i][jj] += av[i] * bv[jj];
            }
        }
    }
    #pragma unroll
    for (int i = 0; i < 8; ++i) {
        float* yp = Y + (n * C_ + o0 + ty * 8 + i) * PS_ + p0 + tx * 8;
        float4 r0 = {acc[i][0], acc[i][1], acc[i][2], acc[i][3]};
        float4 r1 = {acc[i][4], acc[i][5], acc[i][6], acc[i][7]};
        *reinterpret_cast<float4*>(yp) = r0;
        *reinterpret_cast<float4*>(yp + 4) = r1;
    }
}

// ---------------------------------------------------------------------------
// Kernel 4: softmax(25) + CARAFE reassembly. xt channel-innermost (b128 reads).
__global__ __launch_bounds__(256) void k_carafe(const float* __restrict__ Y,
        const float* __restrict__ mask_raw, const float* __restrict__ beff,
        float* __restrict__ xout) {
    int b = blockIdx.x;
    int n = b >> 6, tile = b & 63;
    int sh0 = (tile >> 3) << 3, sw0 = (tile & 7) << 3;
    int tid = threadIdx.x;
    int ty = tid >> 4, tx = tid & 15;
    int oi = sh0 * 2 + ty, oj = sw0 * 2 + tx;
    int h = sh0 + (ty >> 1), w = sw0 + (tx >> 1);
    int sub = ((ty & 1) << 1) | (tx & 1);
    float v[25];
    const float* mp = mask_raw + n * QCH_ * PS_ + h * 64 + w;
    #pragma unroll
    for (int k = 0; k < 25; ++k) v[k] = mp[(k * 4 + sub) * PS_];
    float mx = v[0];
    #pragma unroll
    for (int k = 1; k < 25; ++k) mx = fmaxf(mx, v[k]);
    float s = 0.f;
    #pragma unroll
    for (int k = 0; k < 25; ++k) { v[k] = __expf(v[k] - mx); s += v[k]; }
    float inv = 1.f / s;
    #pragma unroll
    for (int k = 0; k < 25; ++k) v[k] *= inv;

    __shared__ float xt[4608];       // [12x12 px][32 ch]
    int sbase = ((ty >> 1) * 12 + (tx >> 1)) * 32;
    float* hp = xout + n * C_ * PO_ + oi * 128 + oj;
    for (int cg = 0; cg < 8; ++cg) {
        __syncthreads();
        for (int idx = tid; idx < 4608; idx += 256) {
            int sp = idx >> 5, cc = idx & 31;
            int row = sp / 12, col = sp - row * 12;
            int yy = sh0 - 2 + row, xx = sw0 - 2 + col;
            float val = 0.f;
            if ((unsigned)yy < 64u && (unsigned)xx < 64u)
                val = Y[(n * C_ + cg * 32 + cc) * PS_ + yy * 64 + xx];
            xt[sp * 32 + cc] = val;
        }
        __syncthreads();
        #pragma unroll 1
        for (int c4 = 0; c4 < 8; ++c4) {
            int ch = cg * 32 + c4 * 4;
            float ax = beff[ch], ay = beff[ch + 1], az = beff[ch + 2], aw = beff[ch + 3];
            const float* base = xt + sbase + c4 * 4;
            #pragma unroll
            for (int ky = 0; ky < 5; ++ky) {
                #pragma unroll
                for (int kx = 0; kx < 5; ++kx) {
                    float4 yv = *reinterpret_cast<const float4*>(base + (ky * 12 + kx) * 32);
                    float m = v[ky * 5 + kx];
                    ax += m * yv.x; ay += m * yv.y; az += m * yv.z; aw += m * yv.w;
                }
            }
            hp[(ch + 0) * PO_] = ax;
            hp[(ch + 1) * PO_] = ay;
            hp[(ch + 2) * PO_] = az;
            hp[(ch + 3) * PO_] = aw;
        }
    }
}

// ---------------------------------------------------------------------------
// Kernel 5: per-channel BN stats -> scale/shift. One block per channel.
__global__ __launch_bounds__(256) void k_stats(const float* __restrict__ xb,
        const float* __restrict__ gamma, const float* __restrict__ beta,
        float* __restrict__ scale, float* __restrict__ shift) {
    int o = blockIdx.x, tid = threadIdx.x;
    float s = 0.f, s2 = 0.f;
    for (int n = 0; n < 4; ++n) {
        const float* p = xb + (n * C_ + o) * PO_;
        #pragma unroll 4
        for (int i = 0; i < 64; ++i) {
            float v = p[i * 256 + tid];
            s += v; s2 += v * v;
        }
    }
    __shared__ float rs[256], rq[256];
    rs[tid] = s; rq[tid] = s2;
    __syncthreads();
    for (int off = 128; off > 0; off >>= 1) {
        if (tid < off) { rs[tid] += rs[tid + off]; rq[tid] += rq[tid + off]; }
        __syncthreads();
    }
    if (tid == 0) {
        float mean = rs[0] * (1.f / 65536.f);
        float var  = rq[0] * (1.f / 65536.f) - mean * mean;
        float sc = rsqrtf(var + 1e-5f) * gamma[o];
        scale[o] = sc;
        shift[o] = beta[o] - mean * sc;
    }
}

// ---------------------------------------------------------------------------
// Kernel 6: in-place normalize + ReLU on d_out (f32), 4 elems/thread
__global__ __launch_bounds__(256) void k_norm(float* __restrict__ xb,
        const float* __restrict__ scale, const float* __restrict__ shift) {
    int base = (blockIdx.x * 256 + threadIdx.x) * 4;
    int o = (base >> 14) & 255;
    float sc = scale[o], sh = shift[o];
    float4 v = *reinterpret_cast<const float4*>(xb + base);
    v.x = fmaxf(v.x * sc + sh, 0.f);
    v.y = fmaxf(v.y * sc + sh, 0.f);
    v.z = fmaxf(v.z * sc + sh, 0.f);
    v.w = fmaxf(v.w * sc + sh, 0.f);
    *reinterpret_cast<float4*>(xb + base) = v;
}

// ---------------------------------------------------------------------------
extern "C" void kernel_launch(void* const* d_in, const int* in_sizes, int n_in,
                              void* d_out, int out_size, void* d_ws, size_t ws_size,
                              hipStream_t stream) {
    // input order (all float32): low_feature(unused), high_feature, w_cc, b_cc,
    //   w_ce, b_ce, w_conv2, b_conv2, w_bott, gamma, beta
    const float* high    = (const float*)d_in[1];
    const float* w_cc    = (const float*)d_in[2];
    const float* b_cc    = (const float*)d_in[3];
    const float* w_ce    = (const float*)d_in[4];
    const float* b_ce    = (const float*)d_in[5];
    const float* w_conv2 = (const float*)d_in[6];
    const float* b_conv2 = (const float*)d_in[7];
    const float* w_bott  = (const float*)d_in[8];
    const float* gamma   = (const float*)d_in[9];
    const float* beta    = (const float*)d_in[10];

    char* ws = (char*)d_ws;
    float* Weff  = (float*)(ws + 0);          // 256 KiB
    float* beff  = (float*)(ws + 262144);
    float* scale = (float*)(ws + 263168);
    float* shift = (float*)(ws + 264192);
    u16*   Wb    = (u16*)  (ws + 265216);     // 128*576 bf16 = 147456 B
    float* comp  = (float*)(ws + 412672);     // 4 MiB
    float* mask  = (float*)(ws + 4606976);    // 6.25 MiB
    u16*   Icol  = (u16*)  (ws + 11160576);   // 18 MiB (dead after encode)
    float* Y     = (float*)(ws + 11160576);   // 16 MiB, aliases Icol (born after)
    float* xout  = (float*)d_out;             // pre-BN x in d_out, normalized in place

    k_weff       <<<256, 256, 0, stream>>>(w_bott, w_conv2, b_conv2, Weff, beff);
    k_compress   <<<dim3(16, 4, 4), 256, 0, stream>>>(high, w_cc, b_cc, comp);
    k_prepw      <<<288, 256, 0, stream>>>(w_ce, Wb);
    k_im2col     <<<256, 256, 0, stream>>>(comp, Icol);
    k_encode_mfma<<<128, 256, 0, stream>>>(Wb, Icol, b_ce, mask);
    k_ygemm      <<<dim3(32, 2, 4), 256, 0, stream>>>(Weff, high, Y);
    k_carafe     <<<256, 256, 0, stream>>>(Y, mask, beff, xout);
    k_stats      <<<256, 256, 0, stream>>>(xout, gamma, beta, scale, shift);
    k_norm       <<<16384, 256, 0, stream>>>(xout, scale, shift);
}

// Round 5
// 289.681 us; speedup vs baseline: 1.9701x; 1.3462x over previous
//
#include <hip/hip_runtime.h>
#include <hip/hip_bf16.h>

// Problem constants
#define N_    4
#define C_    256
#define PS_   4096      // 64*64 source pixels
#define PO_   16384     // 128*128 output pixels
#define COMP_ 64
#define QCH_  100       // K*K*R*R
#define KK_   25

typedef unsigned short u16;
typedef __attribute__((ext_vector_type(8))) short short8;   // 8 bf16 = 4 VGPR
typedef __attribute__((ext_vector_type(4))) float f32x4;

__device__ __forceinline__ u16 f2bu(float f) {
    __hip_bfloat16 h = __float2bfloat16(f);
    return __builtin_bit_cast(u16, h);
}

// ---------------------------------------------------------------------------
// Kernel 0: W_eff (bf16) = w_bott[:, :256] @ w_conv2 + w_bott[:, 256:]
//           b_eff (f32)  = w_bott[:, :256] @ b_conv2
__global__ __launch_bounds__(256) void k_weff(const float* __restrict__ w_bott,
        const float* __restrict__ w_conv2, const float* __restrict__ b_conv2,
        u16* __restrict__ Weff_bf, float* __restrict__ beff) {
    int o = blockIdx.x, c = threadIdx.x;
    __shared__ float wb[512];
    wb[c]       = w_bott[o * 512 + c];
    wb[c + 256] = w_bott[o * 512 + 256 + c];
    __syncthreads();
    float acc = wb[256 + c];
    #pragma unroll 8
    for (int m = 0; m < 256; ++m)
        acc += wb[m] * w_conv2[m * 256 + c];
    Weff_bf[o * 256 + c] = f2bu(acc);
    if (c == 0) {
        float be = 0.f;
        for (int m = 0; m < 256; ++m) be += wb[m] * b_conv2[m];
        beff[o] = be;
    }
}

// ---------------------------------------------------------------------------
// Kernel 1: weight prep — Wb[128 q][576 u] bf16 (pad q 100->128) and
//           Wcc_bf[64 m][256 c] bf16
__global__ __launch_bounds__(256) void k_prep(const float* __restrict__ w_ce,
        const float* __restrict__ w_cc, u16* __restrict__ Wb, u16* __restrict__ Wcc_bf) {
    int bid = blockIdx.x;
    if (bid < 288) {
        int i = bid * 256 + threadIdx.x;          // over 128*576
        int q = i / 576, u = i - q * 576;
        float v = (q < 100) ? w_ce[q * 576 + u] : 0.f;
        Wb[i] = f2bu(v);
    } else {
        int j = (bid - 288) * 256 + threadIdx.x;  // over 64*256
        Wcc_bf[j] = f2bu(w_cc[j]);
    }
}

// ---------------------------------------------------------------------------
// Kernel 2: channel compressor as MFMA GEMM: M=64, K=256, N=16384.
// B (=high, f32 [c][px]) is cvt+transposed into LDS on the fly.
__global__ __launch_bounds__(256) void k_compress_mfma(const u16* __restrict__ Wcc_bf,
        const float* __restrict__ high, const float* __restrict__ b_cc,
        float* __restrict__ comp) {
    int tid = threadIdx.x;
    int wid = tid >> 6, lane = tid & 63;
    int col = lane & 15, quad = lane >> 4;
    int px0 = blockIdx.x * 128;                 // global pixel over 4 images
    int n = px0 >> 12, pxb = px0 & 4095;
    __shared__ u16 As[64 * 40];
    __shared__ u16 Bs[128 * 40];
    f32x4 acc[8] = {};
    #pragma unroll 1
    for (int k0 = 0; k0 < 256; k0 += 32) {
        __syncthreads();
        // A: 64 rows x 32 k
        {
            int row = tid >> 2, seg = tid & 3;
            short8 av = *reinterpret_cast<const short8*>(Wcc_bf + row * 256 + k0 + seg * 8);
            *reinterpret_cast<short8*>(&As[row * 40 + seg * 8]) = av;
        }
        // B: 32 c x 128 px, transpose+cvt into Bs[px][c]
        #pragma unroll
        for (int it = 0; it < 8; ++it) {
            int idx = it * 256 + tid;           // 0..2047
            int c = (idx >> 7) * 2, px = idx & 127;
            const float* hp = high + (n * C_ + k0 + c) * PS_ + pxb + px;
            unsigned lo = f2bu(hp[0]);
            unsigned hi = f2bu(hp[PS_]);
            *reinterpret_cast<unsigned*>(&Bs[px * 40 + c]) = lo | (hi << 16);
        }
        __syncthreads();
        short8 a = *reinterpret_cast<const short8*>(&As[(wid * 16 + col) * 40 + quad * 8]);
        #pragma unroll
        for (int nt = 0; nt < 8; ++nt) {
            short8 b = *reinterpret_cast<const short8*>(&Bs[(nt * 16 + col) * 40 + quad * 8]);
            acc[nt] = __builtin_amdgcn_mfma_f32_16x16x32_bf16(a, b, acc[nt], 0, 0, 0);
        }
    }
    #pragma unroll
    for (int r = 0; r < 4; ++r) {
        int m = wid * 16 + quad * 4 + r;
        float bias = b_cc[m];
        float* cp = comp + (n * COMP_ + m) * PS_ + pxb + col;
        #pragma unroll
        for (int nt = 0; nt < 8; ++nt)
            cp[nt * 16] = acc[nt][r] + bias;
    }
}

// ---------------------------------------------------------------------------
// Kernel 3: im2col of comp -> Icol[gpx][576 u] bf16, zero-padded 3x3
__global__ __launch_bounds__(256) void k_im2col(const float* __restrict__ comp,
        u16* __restrict__ Icol) {
    int b = blockIdx.x;
    int n = b >> 6, tile = b & 63;
    int ty0 = (tile >> 3) << 3, tx0 = (tile & 7) << 3;
    int tid = threadIdx.x;
    __shared__ float ct[64 * 100];   // 64 ch x 10x10 halo tile
    for (int idx = tid; idx < 6400; idx += 256) {
        int cc = idx / 100, r = idx - cc * 100;
        int yy = ty0 - 1 + r / 10, xx = tx0 - 1 + (r % 10);
        float v = 0.f;
        if ((unsigned)yy < 64u && (unsigned)xx < 64u)
            v = comp[(n * COMP_ + cc) * PS_ + yy * 64 + xx];
        ct[idx] = v;
    }
    __syncthreads();
    int u0 = tid * 2, u1 = u0 + 1;
    int c0 = (unsigned)u0 / 9u, t0 = u0 - c0 * 9;
    int c1 = (unsigned)u1 / 9u, t1 = u1 - c1 * 9;
    int off0 = c0 * 100 + (t0 / 3) * 10 + (t0 % 3);
    int off1 = c1 * 100 + (t1 / 3) * 10 + (t1 % 3);
    int u2 = 512 + tid * 2, u3 = u2 + 1;   // only tid<32
    int c2 = (unsigned)u2 / 9u, t2 = u2 - c2 * 9;
    int c3 = (unsigned)u3 / 9u, t3 = u3 - c3 * 9;
    int off2 = c2 * 100 + (t2 / 3) * 10 + (t2 % 3);
    int off3 = c3 * 100 + (t3 / 3) * 10 + (t3 % 3);
    #pragma unroll 1
    for (int px = 0; px < 64; ++px) {
        int py = px >> 3, pxx = px & 7;
        int base = py * 10 + pxx;
        int gpx = n * PS_ + (ty0 + py) * 64 + tx0 + pxx;
        u16* dst = Icol + gpx * 576;
        unsigned lo = f2bu(ct[off0 + base]);
        unsigned hi = f2bu(ct[off1 + base]);
        *reinterpret_cast<unsigned*>(dst + u0) = lo | (hi << 16);
        if (tid < 32) {
            unsigned lo2 = f2bu(ct[off2 + base]);
            unsigned hi2 = f2bu(ct[off3 + base]);
            *reinterpret_cast<unsigned*>(dst + u2) = lo2 | (hi2 << 16);
        }
    }
}

// ---------------------------------------------------------------------------
// Kernel 4: encoder GEMM via MFMA: M=128(pad 100), K=576, N=16384
__global__ __launch_bounds__(256) void k_encode_mfma(const u16* __restrict__ Wb,
        const u16* __restrict__ Icol, const float* __restrict__ b_ce,
        float* __restrict__ mask_raw) {
    int tid = threadIdx.x;
    int wid = tid >> 6, lane = tid & 63;
    int col = lane & 15, quad = lane >> 4;
    int px0 = blockIdx.x * 128;
    __shared__ u16 As[128 * 40];
    __shared__ u16 Bs[128 * 40];
    f32x4 acc[2][8] = {};
    #pragma unroll 1
    for (int k0 = 0; k0 < 576; k0 += 32) {
        __syncthreads();
        #pragma unroll
        for (int it = 0; it < 2; ++it) {
            int s = tid + it * 256;
            int row = s >> 2, seg = s & 3;
            short8 av = *reinterpret_cast<const short8*>(Wb + row * 576 + k0 + seg * 8);
            *reinterpret_cast<short8*>(&As[row * 40 + seg * 8]) = av;
            short8 bv = *reinterpret_cast<const short8*>(Icol + (px0 + row) * 576 + k0 + seg * 8);
            *reinterpret_cast<short8*>(&Bs[row * 40 + seg * 8]) = bv;
        }
        __syncthreads();
        short8 a0 = *reinterpret_cast<const short8*>(&As[(wid * 32 + col) * 40 + quad * 8]);
        short8 a1 = *reinterpret_cast<const short8*>(&As[(wid * 32 + 16 + col) * 40 + quad * 8]);
        #pragma unroll
        for (int nt = 0; nt < 8; ++nt) {
            short8 b = *reinterpret_cast<const short8*>(&Bs[(nt * 16 + col) * 40 + quad * 8]);
            acc[0][nt] = __builtin_amdgcn_mfma_f32_16x16x32_bf16(a0, b, acc[0][nt], 0, 0, 0);
            acc[1][nt] = __builtin_amdgcn_mfma_f32_16x16x32_bf16(a1, b, acc[1][nt], 0, 0, 0);
        }
    }
    int nimg = px0 >> 12;
    int pbase = px0 & 4095;
    #pragma unroll
    for (int mi = 0; mi < 2; ++mi) {
        int qbase = (wid * 2 + mi) * 16 + quad * 4;
        #pragma unroll
        for (int r = 0; r < 4; ++r) {
            int q = qbase + r;
            if (q < 100) {
                float bias = b_ce[q];
                float* mp = mask_raw + (nimg * QCH_ + q) * PS_ + pbase + col;
                #pragma unroll
                for (int nt = 0; nt < 8; ++nt)
                    mp[nt * 16] = acc[mi][nt][r] + bias;
            }
        }
    }
}

// ---------------------------------------------------------------------------
// Kernel 5: Y GEMM via MFMA: M=256, K=256, N=16384; B=high cvt+transposed.
// Output TRANSPOSED: Y_t[gpx][256 o] f32 (channel-inner, for carafe staging).
__global__ __launch_bounds__(256) void k_ygemm_mfma(const u16* __restrict__ Weff_bf,
        const float* __restrict__ high, float* __restrict__ Yt) {
    int tid = threadIdx.x;
    int wid = tid >> 6, lane = tid & 63;
    int col = lane & 15, quad = lane >> 4;
    int px0 = blockIdx.x * 128;
    int o0 = blockIdx.y * 128;
    int n = px0 >> 12, pxb = px0 & 4095;
    __shared__ u16 As[128 * 40];
    __shared__ u16 Bs[128 * 40];
    f32x4 acc[2][8] = {};
    #pragma unroll 1
    for (int k0 = 0; k0 < 256; k0 += 32) {
        __syncthreads();
        #pragma unroll
        for (int it = 0; it < 2; ++it) {
            int s = tid + it * 256;
            int row = s >> 2, seg = s & 3;
            short8 av = *reinterpret_cast<const short8*>(Weff_bf + (o0 + row) * 256 + k0 + seg * 8);
            *reinterpret_cast<short8*>(&As[row * 40 + seg * 8]) = av;
        }
        #pragma unroll
        for (int it = 0; it < 8; ++it) {
            int idx = it * 256 + tid;           // 0..2047
            int c = (idx >> 7) * 2, px = idx & 127;
            const float* hp = high + (n * C_ + k0 + c) * PS_ + pxb + px;
            unsigned lo = f2bu(hp[0]);
            unsigned hi = f2bu(hp[PS_]);
            *reinterpret_cast<unsigned*>(&Bs[px * 40 + c]) = lo | (hi << 16);
        }
        __syncthreads();
        short8 a0 = *reinterpret_cast<const short8*>(&As[(wid * 32 + col) * 40 + quad * 8]);
        short8 a1 = *reinterpret_cast<const short8*>(&As[(wid * 32 + 16 + col) * 40 + quad * 8]);
        #pragma unroll
        for (int nt = 0; nt < 8; ++nt) {
            short8 b = *reinterpret_cast<const short8*>(&Bs[(nt * 16 + col) * 40 + quad * 8]);
            acc[0][nt] = __builtin_amdgcn_mfma_f32_16x16x32_bf16(a0, b, acc[0][nt], 0, 0, 0);
            acc[1][nt] = __builtin_amdgcn_mfma_f32_16x16x32_bf16(a1, b, acc[1][nt], 0, 0, 0);
        }
    }
    #pragma unroll
    for (int mi = 0; mi < 2; ++mi) {
        int ob = o0 + wid * 32 + mi * 16 + quad * 4;
        #pragma unroll
        for (int nt = 0; nt < 8; ++nt) {
            int gpx = px0 + nt * 16 + col;
            *reinterpret_cast<f32x4*>(Yt + gpx * 256 + ob) = acc[mi][nt];
        }
    }
}

// ---------------------------------------------------------------------------
// Kernel 6: softmax(25) + CARAFE reassembly from Y_t.
// grid (64 tiles, 4 n, 2 channel-halves); 256 thr = 16x16 out px.
// xt stride 36 (bank rotation 4) — conflict-free b128 reads.
__global__ __launch_bounds__(256) void k_carafe(const float* __restrict__ Yt,
        const float* __restrict__ mask_raw, const float* __restrict__ beff,
        float* __restrict__ xout) {
    int tile = blockIdx.x;
    int n = blockIdx.y;
    int half = blockIdx.z;
    int sh0 = (tile >> 3) << 3, sw0 = (tile & 7) << 3;
    int tid = threadIdx.x;
    int ty = tid >> 4, tx = tid & 15;
    int oi = sh0 * 2 + ty, oj = sw0 * 2 + tx;
    int h = sh0 + (ty >> 1), w = sw0 + (tx >> 1);
    int sub = ((ty & 1) << 1) | (tx & 1);
    float v[25];
    const float* mp = mask_raw + n * QCH_ * PS_ + h * 64 + w;
    #pragma unroll
    for (int k = 0; k < 25; ++k) v[k] = mp[(k * 4 + sub) * PS_];
    float mx = v[0];
    #pragma unroll
    for (int k = 1; k < 25; ++k) mx = fmaxf(mx, v[k]);
    float s = 0.f;
    #pragma unroll
    for (int k = 0; k < 25; ++k) { v[k] = __expf(v[k] - mx); s += v[k]; }
    float inv = 1.f / s;
    #pragma unroll
    for (int k = 0; k < 25; ++k) v[k] *= inv;

    __shared__ float xt[144 * 36];   // [12x12 px][32 ch pad 36]
    int sbase = ((ty >> 1) * 12 + (tx >> 1)) * 36;
    float* hp = xout + (n * C_ + half * 128) * PO_ + oi * 128 + oj;
    const float* Yb = Yt + (n * PS_) * 256 + half * 128;
    #pragma unroll 1
    for (int cg = 0; cg < 4; ++cg) {
        __syncthreads();
        #pragma unroll
        for (int it = 0; it < 18; ++it) {
            int idx = it * 256 + tid;          // < 4608
            int cc = idx & 31, sp = idx >> 5;
            int row = sp / 12, colm = sp - row * 12;
            int yy = sh0 - 2 + row, xx = sw0 - 2 + colm;
            float val = 0.f;
            if ((unsigned)yy < 64u && (unsigned)xx < 64u)
                val = Yb[(yy * 64 + xx) * 256 + cg * 32 + cc];
            xt[sp * 36 + cc] = val;
        }
        __syncthreads();
        #pragma unroll 1
        for (int c4 = 0; c4 < 8; ++c4) {
            int ch = half * 128 + cg * 32 + c4 * 4;
            float ax = beff[ch], ay = beff[ch + 1], az = beff[ch + 2], aw = beff[ch + 3];
            const float* base = xt + sbase + c4 * 4;
            #pragma unroll
            for (int ky = 0; ky < 5; ++ky) {
                #pragma unroll
                for (int kx = 0; kx < 5; ++kx) {
                    float4 yv = *reinterpret_cast<const float4*>(base + (ky * 12 + kx) * 36);
                    float m = v[ky * 5 + kx];
                    ax += m * yv.x; ay += m * yv.y; az += m * yv.z; aw += m * yv.w;
                }
            }
            int chl = cg * 32 + c4 * 4;
            hp[(chl + 0) * PO_] = ax;
            hp[(chl + 1) * PO_] = ay;
            hp[(chl + 2) * PO_] = az;
            hp[(chl + 3) * PO_] = aw;
        }
    }
}

// ---------------------------------------------------------------------------
// Kernel 7: per-channel BN stats -> scale/shift. One block per channel.
__global__ __launch_bounds__(256) void k_stats(const float* __restrict__ xb,
        const float* __restrict__ gamma, const float* __restrict__ beta,
        float* __restrict__ scale, float* __restrict__ shift) {
    int o = blockIdx.x, tid = threadIdx.x;
    float s = 0.f, s2 = 0.f;
    for (int n = 0; n < 4; ++n) {
        const float* p = xb + (n * C_ + o) * PO_;
        #pragma unroll 4
        for (int i = 0; i < 64; ++i) {
            float v = p[i * 256 + tid];
            s += v; s2 += v * v;
        }
    }
    __shared__ float rs[256], rq[256];
    rs[tid] = s; rq[tid] = s2;
    __syncthreads();
    for (int off = 128; off > 0; off >>= 1) {
        if (tid < off) { rs[tid] += rs[tid + off]; rq[tid] += rq[tid + off]; }
        __syncthreads();
    }
    if (tid == 0) {
        float mean = rs[0] * (1.f / 65536.f);
        float var  = rq[0] * (1.f / 65536.f) - mean * mean;
        float sc = rsqrtf(var + 1e-5f) * gamma[o];
        scale[o] = sc;
        shift[o] = beta[o] - mean * sc;
    }
}

// ---------------------------------------------------------------------------
// Kernel 8: in-place normalize + ReLU on d_out (f32), 4 elems/thread
__global__ __launch_bounds__(256) void k_norm(float* __restrict__ xb,
        const float* __restrict__ scale, const float* __restrict__ shift) {
    int base = (blockIdx.x * 256 + threadIdx.x) * 4;
    int o = (base >> 14) & 255;
    float sc = scale[o], sh = shift[o];
    float4 v = *reinterpret_cast<const float4*>(xb + base);
    v.x = fmaxf(v.x * sc + sh, 0.f);
    v.y = fmaxf(v.y * sc + sh, 0.f);
    v.z = fmaxf(v.z * sc + sh, 0.f);
    v.w = fmaxf(v.w * sc + sh, 0.f);
    *reinterpret_cast<float4*>(xb + base) = v;
}

// ---------------------------------------------------------------------------
extern "C" void kernel_launch(void* const* d_in, const int* in_sizes, int n_in,
                              void* d_out, int out_size, void* d_ws, size_t ws_size,
                              hipStream_t stream) {
    // input order (all float32): low_feature(unused), high_feature, w_cc, b_cc,
    //   w_ce, b_ce, w_conv2, b_conv2, w_bott, gamma, beta
    const float* high    = (const float*)d_in[1];
    const float* w_cc    = (const float*)d_in[2];
    const float* b_cc    = (const float*)d_in[3];
    const float* w_ce    = (const float*)d_in[4];
    const float* b_ce    = (const float*)d_in[5];
    const float* w_conv2 = (const float*)d_in[6];
    const float* b_conv2 = (const float*)d_in[7];
    const float* w_bott  = (const float*)d_in[8];
    const float* gamma   = (const float*)d_in[9];
    const float* beta    = (const float*)d_in[10];

    char* ws = (char*)d_ws;
    float* beff    = (float*)(ws + 0);           // 1 KiB
    float* scale   = (float*)(ws + 1024);
    float* shift   = (float*)(ws + 2048);
    u16*   Weff_bf = (u16*)  (ws + 3072);        // 256*256*2 = 131072
    u16*   Wcc_bf  = (u16*)  (ws + 134144);      // 64*256*2 = 32768
    u16*   Wb      = (u16*)  (ws + 166912);      // 128*576*2 = 147456
    float* mask    = (float*)(ws + 314368);      // 6.55 MB (comp aliased inside)
    float* comp    = (float*)(ws + 314368);      // 4 MB, dead before mask written
    u16*   Icol    = (u16*)  (ws + 6867968);     // 18.9 MB
    float* Yt      = (float*)(ws + 6867968);     // 16.8 MB, aliases Icol (born after)
    float* xout    = (float*)d_out;              // pre-BN x, normalized in place

    k_weff         <<<256, 256, 0, stream>>>(w_bott, w_conv2, b_conv2, Weff_bf, beff);
    k_prep         <<<352, 256, 0, stream>>>(w_ce, w_cc, Wb, Wcc_bf);
    k_compress_mfma<<<128, 256, 0, stream>>>(Wcc_bf, high, b_cc, comp);
    k_im2col       <<<256, 256, 0, stream>>>(comp, Icol);
    k_encode_mfma  <<<128, 256, 0, stream>>>(Wb, Icol, b_ce, mask);
    k_ygemm_mfma   <<<dim3(128, 2), 256, 0, stream>>>(Weff_bf, high, Yt);
    k_carafe       <<<dim3(64, 4, 2), 256, 0, stream>>>(Yt, mask, beff, xout);
    k_stats        <<<256, 256, 0, stream>>>(xout, gamma, beta, scale, shift);
    k_norm         <<<16384, 256, 0, stream>>>(xout, scale, shift);
}

// Round 6
// 272.117 us; speedup vs baseline: 2.0973x; 1.0645x over previous
//
#include <hip/hip_runtime.h>
#include <hip/hip_bf16.h>

// Problem constants
#define N_    4
#define C_    256
#define PS_   4096      // 64*64 source pixels
#define PO_   16384     // 128*128 output pixels
#define COMP_ 64
#define QCH_  100       // K*K*R*R

typedef unsigned short u16;
typedef __attribute__((ext_vector_type(8))) short short8;   // 8 bf16 = 4 VGPR
typedef __attribute__((ext_vector_type(4))) float f32x4;

__device__ __forceinline__ u16 f2bu(float f) {
    __hip_bfloat16 h = __float2bfloat16(f);
    return __builtin_bit_cast(u16, h);
}
__device__ __forceinline__ float bits2f(unsigned u) {
    union { unsigned i; float f; } v; v.i = u; return v.f;
}

// ---------------------------------------------------------------------------
// Kernel 0 (merged prep):
//  bid<256 : Weff_bf[o][c] = bf16( w_bott[o,:256]@w_conv2 + w_bott[o,256+c] ), beff
//  bid<544 : Wb[128 q][576 u] bf16 (pad q 100->128)
//  else    : Wcc_bf[64 m][256 c] bf16
__global__ __launch_bounds__(256) void k_prep(const float* __restrict__ w_bott,
        const float* __restrict__ w_conv2, const float* __restrict__ b_conv2,
        const float* __restrict__ w_ce, const float* __restrict__ w_cc,
        u16* __restrict__ Weff_bf, float* __restrict__ beff,
        u16* __restrict__ Wb, u16* __restrict__ Wcc_bf) {
    int bid = blockIdx.x;
    if (bid < 256) {
        int o = bid, c = threadIdx.x;
        __shared__ float wb[512];
        wb[c]       = w_bott[o * 512 + c];
        wb[c + 256] = w_bott[o * 512 + 256 + c];
        __syncthreads();
        float acc = wb[256 + c];
        #pragma unroll 8
        for (int m = 0; m < 256; ++m)
            acc += wb[m] * w_conv2[m * 256 + c];
        Weff_bf[o * 256 + c] = f2bu(acc);
        if (c == 0) {
            float be = 0.f;
            for (int m = 0; m < 256; ++m) be += wb[m] * b_conv2[m];
            beff[o] = be;
        }
    } else if (bid < 544) {
        int i = (bid - 256) * 256 + threadIdx.x;   // over 128*576
        int q = i / 576, u = i - q * 576;
        float v = (q < 100) ? w_ce[q * 576 + u] : 0.f;
        Wb[i] = f2bu(v);
    } else {
        int j = (bid - 544) * 256 + threadIdx.x;   // over 64*256
        Wcc_bf[j] = f2bu(w_cc[j]);
    }
}

// ---------------------------------------------------------------------------
// Kernel 1: channel compressor MFMA GEMM: M=64, K=256, N=64/block (256 blocks)
__global__ __launch_bounds__(256) void k_compress_mfma(const u16* __restrict__ Wcc_bf,
        const float* __restrict__ high, const float* __restrict__ b_cc,
        float* __restrict__ comp) {
    int tid = threadIdx.x;
    int wid = tid >> 6, lane = tid & 63;
    int col = lane & 15, quad = lane >> 4;
    int px0 = blockIdx.x * 64;
    int n = px0 >> 12, pxb = px0 & 4095;
    __shared__ u16 As[64 * 40];
    __shared__ u16 Bs[64 * 40];
    f32x4 acc[4] = {};
    #pragma unroll 1
    for (int k0 = 0; k0 < 256; k0 += 32) {
        __syncthreads();
        {   // A: 64 rows x 32 k
            int row = tid >> 2, seg = tid & 3;
            short8 av = *reinterpret_cast<const short8*>(Wcc_bf + row * 256 + k0 + seg * 8);
            *reinterpret_cast<short8*>(&As[row * 40 + seg * 8]) = av;
        }
        #pragma unroll
        for (int it = 0; it < 4; ++it) {   // B: 32 c x 64 px, transpose+cvt
            int idx = it * 256 + tid;       // 0..1023
            int c = (idx >> 6) * 2, px = idx & 63;
            const float* hp = high + (n * C_ + k0 + c) * PS_ + pxb + px;
            unsigned lo = f2bu(hp[0]);
            unsigned hi = f2bu(hp[PS_]);
            *reinterpret_cast<unsigned*>(&Bs[px * 40 + c]) = lo | (hi << 16);
        }
        __syncthreads();
        short8 a = *reinterpret_cast<const short8*>(&As[(wid * 16 + col) * 40 + quad * 8]);
        #pragma unroll
        for (int nt = 0; nt < 4; ++nt) {
            short8 b = *reinterpret_cast<const short8*>(&Bs[(nt * 16 + col) * 40 + quad * 8]);
            acc[nt] = __builtin_amdgcn_mfma_f32_16x16x32_bf16(a, b, acc[nt], 0, 0, 0);
        }
    }
    #pragma unroll
    for (int r = 0; r < 4; ++r) {
        int m = wid * 16 + quad * 4 + r;
        float bias = b_cc[m];
        float* cp = comp + (n * COMP_ + m) * PS_ + pxb + col;
        #pragma unroll
        for (int nt = 0; nt < 4; ++nt)
            cp[nt * 16] = acc[nt][r] + bias;
    }
}

// ---------------------------------------------------------------------------
// Kernel 2: im2col of comp -> Icol[gpx][576 u] bf16, zero-padded 3x3
__global__ __launch_bounds__(256) void k_im2col(const float* __restrict__ comp,
        u16* __restrict__ Icol) {
    int b = blockIdx.x;
    int n = b >> 6, tile = b & 63;
    int ty0 = (tile >> 3) << 3, tx0 = (tile & 7) << 3;
    int tid = threadIdx.x;
    __shared__ float ct[64 * 100];   // 64 ch x 10x10 halo tile
    for (int idx = tid; idx < 6400; idx += 256) {
        int cc = idx / 100, r = idx - cc * 100;
        int yy = ty0 - 1 + r / 10, xx = tx0 - 1 + (r % 10);
        float v = 0.f;
        if ((unsigned)yy < 64u && (unsigned)xx < 64u)
            v = comp[(n * COMP_ + cc) * PS_ + yy * 64 + xx];
        ct[idx] = v;
    }
    __syncthreads();
    int u0 = tid * 2, u1 = u0 + 1;
    int c0 = (unsigned)u0 / 9u, t0 = u0 - c0 * 9;
    int c1 = (unsigned)u1 / 9u, t1 = u1 - c1 * 9;
    int off0 = c0 * 100 + (t0 / 3) * 10 + (t0 % 3);
    int off1 = c1 * 100 + (t1 / 3) * 10 + (t1 % 3);
    int u2 = 512 + tid * 2, u3 = u2 + 1;   // only tid<32
    int c2 = (unsigned)u2 / 9u, t2 = u2 - c2 * 9;
    int c3 = (unsigned)u3 / 9u, t3 = u3 - c3 * 9;
    int off2 = c2 * 100 + (t2 / 3) * 10 + (t2 % 3);
    int off3 = c3 * 100 + (t3 / 3) * 10 + (t3 % 3);
    #pragma unroll 1
    for (int px = 0; px < 64; ++px) {
        int py = px >> 3, pxx = px & 7;
        int base = py * 10 + pxx;
        int gpx = n * PS_ + (ty0 + py) * 64 + tx0 + pxx;
        u16* dst = Icol + gpx * 576;
        unsigned lo = f2bu(ct[off0 + base]);
        unsigned hi = f2bu(ct[off1 + base]);
        *reinterpret_cast<unsigned*>(dst + u0) = lo | (hi << 16);
        if (tid < 32) {
            unsigned lo2 = f2bu(ct[off2 + base]);
            unsigned hi2 = f2bu(ct[off3 + base]);
            *reinterpret_cast<unsigned*>(dst + u2) = lo2 | (hi2 << 16);
        }
    }
}

// ---------------------------------------------------------------------------
// Kernel 3: encoder MFMA GEMM: M=128(pad 100), K=576, N=64/block (256 blocks)
__global__ __launch_bounds__(256) void k_encode_mfma(const u16* __restrict__ Wb,
        const u16* __restrict__ Icol, const float* __restrict__ b_ce,
        float* __restrict__ mask_raw) {
    int tid = threadIdx.x;
    int wid = tid >> 6, lane = tid & 63;
    int col = lane & 15, quad = lane >> 4;
    int px0 = blockIdx.x * 64;
    int n = px0 >> 12, pxb = px0 & 4095;
    __shared__ u16 As[128 * 40];
    __shared__ u16 Bs[64 * 40];
    f32x4 acc[2][4] = {};
    #pragma unroll 1
    for (int k0 = 0; k0 < 576; k0 += 32) {
        __syncthreads();
        #pragma unroll
        for (int it = 0; it < 2; ++it) {   // A: 128 rows x 4 segs
            int s = tid + it * 256;
            int row = s >> 2, seg = s & 3;
            short8 av = *reinterpret_cast<const short8*>(Wb + row * 576 + k0 + seg * 8);
            *reinterpret_cast<short8*>(&As[row * 40 + seg * 8]) = av;
        }
        {   // B: 64 rows x 4 segs
            int row = tid >> 2, seg = tid & 3;
            short8 bv = *reinterpret_cast<const short8*>(Icol + (px0 + row) * 576 + k0 + seg * 8);
            *reinterpret_cast<short8*>(&Bs[row * 40 + seg * 8]) = bv;
        }
        __syncthreads();
        short8 a0 = *reinterpret_cast<const short8*>(&As[(wid * 32 + col) * 40 + quad * 8]);
        short8 a1 = *reinterpret_cast<const short8*>(&As[(wid * 32 + 16 + col) * 40 + quad * 8]);
        #pragma unroll
        for (int nt = 0; nt < 4; ++nt) {
            short8 b = *reinterpret_cast<const short8*>(&Bs[(nt * 16 + col) * 40 + quad * 8]);
            acc[0][nt] = __builtin_amdgcn_mfma_f32_16x16x32_bf16(a0, b, acc[0][nt], 0, 0, 0);
            acc[1][nt] = __builtin_amdgcn_mfma_f32_16x16x32_bf16(a1, b, acc[1][nt], 0, 0, 0);
        }
    }
    #pragma unroll
    for (int mi = 0; mi < 2; ++mi) {
        int qbase = (wid * 2 + mi) * 16 + quad * 4;
        #pragma unroll
        for (int r = 0; r < 4; ++r) {
            int q = qbase + r;
            if (q < 100) {
                float bias = b_ce[q];
                float* mp = mask_raw + (n * QCH_ + q) * PS_ + pxb + col;
                #pragma unroll
                for (int nt = 0; nt < 4; ++nt)
                    mp[nt * 16] = acc[mi][nt][r] + bias;
            }
        }
    }
}

// ---------------------------------------------------------------------------
// Kernel 4: Y GEMM MFMA: M=256, K=256, N=16384. Output Yt[gpx][256 ch] BF16.
__global__ __launch_bounds__(256) void k_ygemm_mfma(const u16* __restrict__ Weff_bf,
        const float* __restrict__ high, u16* __restrict__ Yt) {
    int tid = threadIdx.x;
    int wid = tid >> 6, lane = tid & 63;
    int col = lane & 15, quad = lane >> 4;
    int px0 = blockIdx.x * 128;
    int o0 = blockIdx.y * 128;
    int n = px0 >> 12, pxb = px0 & 4095;
    __shared__ u16 As[128 * 40];
    __shared__ u16 Bs[128 * 40];
    f32x4 acc[2][8] = {};
    #pragma unroll 1
    for (int k0 = 0; k0 < 256; k0 += 32) {
        __syncthreads();
        #pragma unroll
        for (int it = 0; it < 2; ++it) {
            int s = tid + it * 256;
            int row = s >> 2, seg = s & 3;
            short8 av = *reinterpret_cast<const short8*>(Weff_bf + (o0 + row) * 256 + k0 + seg * 8);
            *reinterpret_cast<short8*>(&As[row * 40 + seg * 8]) = av;
        }
        #pragma unroll
        for (int it = 0; it < 8; ++it) {
            int idx = it * 256 + tid;           // 0..2047
            int c = (idx >> 7) * 2, px = idx & 127;
            const float* hp = high + (n * C_ + k0 + c) * PS_ + pxb + px;
            unsigned lo = f2bu(hp[0]);
            unsigned hi = f2bu(hp[PS_]);
            *reinterpret_cast<unsigned*>(&Bs[px * 40 + c]) = lo | (hi << 16);
        }
        __syncthreads();
        short8 a0 = *reinterpret_cast<const short8*>(&As[(wid * 32 + col) * 40 + quad * 8]);
        short8 a1 = *reinterpret_cast<const short8*>(&As[(wid * 32 + 16 + col) * 40 + quad * 8]);
        #pragma unroll
        for (int nt = 0; nt < 8; ++nt) {
            short8 b = *reinterpret_cast<const short8*>(&Bs[(nt * 16 + col) * 40 + quad * 8]);
            acc[0][nt] = __builtin_amdgcn_mfma_f32_16x16x32_bf16(a0, b, acc[0][nt], 0, 0, 0);
            acc[1][nt] = __builtin_amdgcn_mfma_f32_16x16x32_bf16(a1, b, acc[1][nt], 0, 0, 0);
        }
    }
    #pragma unroll
    for (int mi = 0; mi < 2; ++mi) {
        int ob = o0 + wid * 32 + mi * 16 + quad * 4;
        #pragma unroll
        for (int nt = 0; nt < 8; ++nt) {
            int gpx = px0 + nt * 16 + col;
            unsigned lo = f2bu(acc[mi][nt][0]) | ((unsigned)f2bu(acc[mi][nt][1]) << 16);
            unsigned hi = f2bu(acc[mi][nt][2]) | ((unsigned)f2bu(acc[mi][nt][3]) << 16);
            uint2 pk; pk.x = lo; pk.y = hi;
            *reinterpret_cast<uint2*>(Yt + (size_t)gpx * 256 + ob) = pk;
        }
    }
}

// ---------------------------------------------------------------------------
// Kernel 5: softmax(25) + CARAFE reassembly, 4-sub sharing.
// grid (64 tiles, 4 n, 2 ch-halves); 256 thr = 64 source px x 4 ch-groups.
__global__ __launch_bounds__(256) void k_carafe(const u16* __restrict__ Yt,
        const float* __restrict__ mask_raw, const float* __restrict__ beff,
        float* __restrict__ xout) {
    int tile = blockIdx.x, n = blockIdx.y, half = blockIdx.z;
    int sh0 = (tile >> 3) << 3, sw0 = (tile & 7) << 3;
    int tid = threadIdx.x;
    int px = tid & 63, g = tid >> 6;
    int ly = px >> 3, lx = px & 7;
    int h = sh0 + ly, w = sw0 + lx;

    __shared__ float mt[6400];       // [q][64 px]   25.6 KB
    __shared__ u16 xt[144 * 68];     // [halo px][64 ch pad]  19.6 KB

    for (int idx = tid; idx < 6400; idx += 256) {
        int q = idx >> 6, p = idx & 63;
        mt[idx] = mask_raw[(n * QCH_ + q) * PS_ + (sh0 + (p >> 3)) * 64 + sw0 + (p & 7)];
    }
    __syncthreads();

    float vs[4][25];
    #pragma unroll
    for (int s = 0; s < 4; ++s) {
        #pragma unroll
        for (int k = 0; k < 25; ++k) vs[s][k] = mt[(k * 4 + s) * 64 + px];
        float mx = vs[s][0];
        #pragma unroll
        for (int k = 1; k < 25; ++k) mx = fmaxf(mx, vs[s][k]);
        float sum = 0.f;
        #pragma unroll
        for (int k = 0; k < 25; ++k) { vs[s][k] = __expf(vs[s][k] - mx); sum += vs[s][k]; }
        float inv = 1.f / sum;
        #pragma unroll
        for (int k = 0; k < 25; ++k) vs[s][k] *= inv;
    }

    const u16* Yb = Yt + (size_t)n * PS_ * 256;
    float* hp_base = xout + (size_t)(n * C_) * PO_;
    #pragma unroll 1
    for (int chunk = 0; chunk < 2; ++chunk) {
        int ch0 = half * 128 + chunk * 64;
        __syncthreads();
        for (int idx = tid; idx < 1152; idx += 256) {
            int sp = idx >> 3, seg = idx & 7;
            int row = sp / 12, colm = sp - row * 12;
            int yy = sh0 - 2 + row, xx = sw0 - 2 + colm;
            short8 val = {};
            if ((unsigned)yy < 64u && (unsigned)xx < 64u)
                val = *reinterpret_cast<const short8*>(Yb + (size_t)(yy * 64 + xx) * 256 + ch0 + seg * 8);
            *reinterpret_cast<short8*>(&xt[sp * 68 + seg * 8]) = val;
        }
        __syncthreads();
        #pragma unroll 1
        for (int cq = 0; cq < 4; ++cq) {
            int c = g * 16 + cq * 4;        // within chunk
            int ch = ch0 + c;
            f32x4 bv = *reinterpret_cast<const f32x4*>(beff + ch);
            float a_[4][4];
            #pragma unroll
            for (int s = 0; s < 4; ++s) {
                a_[s][0] = bv[0]; a_[s][1] = bv[1]; a_[s][2] = bv[2]; a_[s][3] = bv[3];
            }
            const u16* bp = xt + (ly * 12 + lx) * 68 + c;
            #pragma unroll
            for (int ky = 0; ky < 5; ++ky) {
                #pragma unroll
                for (int kx = 0; kx < 5; ++kx) {
                    uint2 rv = *reinterpret_cast<const uint2*>(bp + (ky * 12 + kx) * 68);
                    float f0 = bits2f(rv.x << 16);
                    float f1 = bits2f(rv.x & 0xffff0000u);
                    float f2 = bits2f(rv.y << 16);
                    float f3 = bits2f(rv.y & 0xffff0000u);
                    int k = ky * 5 + kx;
                    #pragma unroll
                    for (int s = 0; s < 4; ++s) {
                        float m = vs[s][k];
                        a_[s][0] += m * f0; a_[s][1] += m * f1;
                        a_[s][2] += m * f2; a_[s][3] += m * f3;
                    }
                }
            }
            #pragma unroll
            for (int i = 0; i < 4; ++i) {
                float* op = hp_base + (size_t)(ch + i) * PO_ + (2 * h) * 128 + 2 * w;
                float2 r0; r0.x = a_[0][i]; r0.y = a_[1][i];
                float2 r1; r1.x = a_[2][i]; r1.y = a_[3][i];
                *reinterpret_cast<float2*>(op) = r0;
                *reinterpret_cast<float2*>(op + 128) = r1;
            }
        }
    }
}

// ---------------------------------------------------------------------------
// Kernel 6: per-channel BN stats -> scale/shift. One block per channel.
__global__ __launch_bounds__(256) void k_stats(const float* __restrict__ xb,
        const float* __restrict__ gamma, const float* __restrict__ beta,
        float* __restrict__ scale, float* __restrict__ shift) {
    int o = blockIdx.x, tid = threadIdx.x;
    float s = 0.f, s2 = 0.f;
    for (int n = 0; n < 4; ++n) {
        const float* p = xb + (size_t)(n * C_ + o) * PO_;
        #pragma unroll 4
        for (int i = 0; i < 64; ++i) {
            float v = p[i * 256 + tid];
            s += v; s2 += v * v;
        }
    }
    __shared__ float rs[256], rq[256];
    rs[tid] = s; rq[tid] = s2;
    __syncthreads();
    for (int off = 128; off > 0; off >>= 1) {
        if (tid < off) { rs[tid] += rs[tid + off]; rq[tid] += rq[tid + off]; }
        __syncthreads();
    }
    if (tid == 0) {
        float mean = rs[0] * (1.f / 65536.f);
        float var  = rq[0] * (1.f / 65536.f) - mean * mean;
        float sc = rsqrtf(var + 1e-5f) * gamma[o];
        scale[o] = sc;
        shift[o] = beta[o] - mean * sc;
    }
}

// ---------------------------------------------------------------------------
// Kernel 7: in-place normalize + ReLU on d_out (f32), 4 elems/thread
__global__ __launch_bounds__(256) void k_norm(float* __restrict__ xb,
        const float* __restrict__ scale, const float* __restrict__ shift) {
    int base = (blockIdx.x * 256 + threadIdx.x) * 4;
    int o = (base >> 14) & 255;
    float sc = scale[o], sh = shift[o];
    float4 v = *reinterpret_cast<const float4*>(xb + base);
    v.x = fmaxf(v.x * sc + sh, 0.f);
    v.y = fmaxf(v.y * sc + sh, 0.f);
    v.z = fmaxf(v.z * sc + sh, 0.f);
    v.w = fmaxf(v.w * sc + sh, 0.f);
    *reinterpret_cast<float4*>(xb + base) = v;
}

// ---------------------------------------------------------------------------
extern "C" void kernel_launch(void* const* d_in, const int* in_sizes, int n_in,
                              void* d_out, int out_size, void* d_ws, size_t ws_size,
                              hipStream_t stream) {
    const float* high    = (const float*)d_in[1];
    const float* w_cc    = (const float*)d_in[2];
    const float* b_cc    = (const float*)d_in[3];
    const float* w_ce    = (const float*)d_in[4];
    const float* b_ce    = (const float*)d_in[5];
    const float* w_conv2 = (const float*)d_in[6];
    const float* b_conv2 = (const float*)d_in[7];
    const float* w_bott  = (const float*)d_in[8];
    const float* gamma   = (const float*)d_in[9];
    const float* beta    = (const float*)d_in[10];

    char* ws = (char*)d_ws;
    float* beff    = (float*)(ws + 0);
    float* scale   = (float*)(ws + 1024);
    float* shift   = (float*)(ws + 2048);
    u16*   Weff_bf = (u16*)  (ws + 3072);        // 131072 B
    u16*   Wcc_bf  = (u16*)  (ws + 134144);      // 32768 B
    u16*   Wb      = (u16*)  (ws + 166912);      // 147456 B
    float* mask    = (float*)(ws + 314368);      // 6.55 MB (comp aliased: comp dead before encode writes)
    float* comp    = (float*)(ws + 314368);      // 4 MB
    u16*   Icol    = (u16*)  (ws + 6867968);     // 18.9 MB (dead after encode)
    u16*   Yt      = (u16*)  (ws + 6867968);     // 8.4 MB bf16, aliases Icol
    float* xout    = (float*)d_out;              // pre-BN x, normalized in place

    k_prep         <<<608, 256, 0, stream>>>(w_bott, w_conv2, b_conv2, w_ce, w_cc,
                                             Weff_bf, beff, Wb, Wcc_bf);
    k_compress_mfma<<<256, 256, 0, stream>>>(Wcc_bf, high, b_cc, comp);
    k_im2col       <<<256, 256, 0, stream>>>(comp, Icol);
    k_encode_mfma  <<<256, 256, 0, stream>>>(Wb, Icol, b_ce, mask);
    k_ygemm_mfma   <<<dim3(128, 2), 256, 0, stream>>>(Weff_bf, high, Yt);
    k_carafe       <<<dim3(64, 4, 2), 256, 0, stream>>>(Yt, mask, beff, xout);
    k_stats        <<<256, 256, 0, stream>>>(xout, gamma, beta, scale, shift);
    k_norm         <<<16384, 256, 0, stream>>>(xout, scale, shift);
}